// Round 19
// baseline (103.939 us; speedup 1.0000x reference)
//
#include <hip/hip_runtime.h>
#include <hip/hip_bf16.h>
#include <hip/hip_fp16.h>

// Problem constants (fixed by setup_inputs)
#define BATCH 16
#define NCH 3
#define H 512
#define W 512
#define HW (H * W)          // 262144 = 2^18
#define PAD 7
#define K 26                // int(0.0001 * 512 * 512)
#define NSUB 1024           // subs (4 rows x 64 cols = 256 px) per batch
#define NPAIR 32            // 2 maps x 16 batches
#define BK (BATCH * K)      // 416
#define CAP 32768           // candidate list capacity per pair
#define LDSCAP 6144         // merge LDS tile (48 KB)

#define TH1 16              // pool tile height
#define ROWS1 30            // TH1 + 14
#define SHP 68              // padded LDS stride for h-pool rows (64 used)

#define FINF __builtin_inff()

// monotone float->u32 key (order-preserving for all floats)
__device__ __forceinline__ unsigned mkey(float f) {
    unsigned u = __float_as_uint(f);
    unsigned m = (unsigned)(((int)u) >> 31) | 0x80000000u;
    return u ^ m;
}

__device__ __forceinline__ unsigned short f2h(float f) {
    __half h = __float2half(f);
    return *reinterpret_cast<unsigned short*>(&h);
}
__device__ __forceinline__ float h2f(unsigned short s) {
    __half h = *reinterpret_cast<__half*>(&s);
    return __half2float(h);
}

__device__ __forceinline__ unsigned long long shfl_xor_u64(unsigned long long v, int m) {
    int lo = __shfl_xor((int)(unsigned)(v & 0xFFFFFFFFull), m);
    int hi = __shfl_xor((int)(unsigned)(v >> 32), m);
    return ((unsigned long long)(unsigned)hi << 32) | (unsigned)lo;
}

template <bool MX>
__device__ __forceinline__ float op(float a, float b) { return MX ? fmaxf(a, b) : fminf(a, b); }
template <bool MX>
__device__ __forceinline__ float4 op4(float4 a, float4 b) {
    return make_float4(op<MX>(a.x, b.x), op<MX>(a.y, b.y), op<MX>(a.z, b.z), op<MX>(a.w, b.w));
}

// horizontal 15-window pool of a 4-output group from 5 clamped-base float4s
template <bool MX>
__device__ __forceinline__ float4 hquad(float4 fA, float4 fB, float4 fC, float4 fD, float4 fE) {
    float4 m4 = op4<MX>(op4<MX>(fB, fC), fD);
    float tm = op<MX>(op<MX>(m4.x, m4.y), op<MX>(m4.z, m4.w));
    return make_float4(
        op<MX>(tm, op<MX>(fA.y, op<MX>(fA.z, fA.w))),
        op<MX>(tm, op<MX>(fA.z, op<MX>(fA.w, fE.x))),
        op<MX>(tm, op<MX>(fA.w, op<MX>(fE.x, fE.y))),
        op<MX>(tm, op<MX>(fE.x, op<MX>(fE.y, fE.z))));
}

// v-pool of 2 consecutive output rows from 16 LDS rows (14-row shared core)
template <bool MX>
__device__ __forceinline__ void vpool2(const float* __restrict__ sH, int vy, int vx,
                                       float4 o[2]) {
    const float* p0 = sH + vy * SHP + vx;
    float4 t4 = *(const float4*)(p0 + SHP);
#pragma unroll
    for (int j = 2; j <= 14; ++j) t4 = op4<MX>(t4, *(const float4*)(p0 + j * SHP));
    float4 r0 = *(const float4*)(p0);
    float4 r15 = *(const float4*)(p0 + 15 * SHP);
    o[0] = op4<MX>(r0, t4);
    o[1] = op4<MX>(t4, r15);
}

// ---------------------------------------------------------------------------
// K1 (r12/r14/r16-proven): 64x16 tiles, LDS 16.3 KB -> 8 blocks/CU, grid 4096
// = exactly 2 full rounds. Per channel: h-pool straight from global (5
// clamped-base float4 loads per 4-output group == exact clamp-to-edge), max
// AND min from the same loads into two LDS buffers; x->out copy rides on the
// center float4. v-pool half-split: u<128 -> max map (fp16 Vmax + bc keys),
// u>=128 -> min map (dc keys). Emits per-sub (4x64) key maxima. Blocks 0..47
// also zero nCand / A2sum / done (stream order guarantees visibility).
__global__ __launch_bounds__(256, 8) void pool_maps_kernel(
    const float* __restrict__ x, unsigned short* __restrict__ vmaxh,
    unsigned* __restrict__ dcK, unsigned* __restrict__ bcK,
    unsigned* __restrict__ subkey, float* __restrict__ out,
    int* __restrict__ nCand, float* __restrict__ A2sum, int* __restrict__ done) {
    __shared__ __align__(16) float sHmax[ROWS1 * SHP];
    __shared__ __align__(16) float sHmin[ROWS1 * SHP];
    int blk = blockIdx.x;
    if (threadIdx.x == 0) {
        if (blk < NPAIR) { nCand[blk] = 0; done[blk] = 0; }
        if (blk < BATCH * NCH) A2sum[blk] = 0.0f;
    }
    int b = blk >> 8;
    int tile = blk & 255;          // 8 cols x 32 rows of tiles
    int tx0 = (tile & 7) << 6;
    int ty0 = (tile >> 3) << 4;
    int u = threadIdx.x;
    int half = u >> 7;      // 0: max map (bc + Vmax), 1: min map (dc)
    int v = u & 127;
    int rg = v >> 4;        // 0..7 row-pairs
    int cg = v & 15;
    int vx = cg << 2;
    int vy = rg << 1;       // 0,2,..,14
    float4 acc[2];
    float ainit = half ? FINF : -FINF;
    acc[0] = acc[1] = make_float4(ainit, ainit, ainit, ainit);

    for (int c = 0; c < NCH; ++c) {
        const float* xp = x + (((size_t)(b * NCH + c)) << 18);
        float* outp = out + (((size_t)(b * 4 + c)) << 18);
        for (int it = u; it < ROWS1 * 16; it += 256) {
            int r = it >> 4;
            int x0 = (it & 15) << 2;
            int gy = ty0 - PAD + r;
            gy = gy < 0 ? 0 : (gy > H - 1 ? H - 1 : gy);
            const float* rowp = xp + (gy << 9);
            int gx0 = tx0 + x0;
            int aB = gx0 - 8; aB = aB < 0 ? 0 : aB;
            int bB = gx0 - 4; bB = bB < 0 ? 0 : bB;
            int dB = gx0 + 4; dB = dB > W - 4 ? W - 4 : dB;
            int eB = gx0 + 8; eB = eB > W - 4 ? W - 4 : eB;
            float4 fA = *(const float4*)(rowp + aB);
            float4 fB = *(const float4*)(rowp + bB);
            float4 fC = *(const float4*)(rowp + gx0);
            float4 fD = *(const float4*)(rowp + dB);
            float4 fE = *(const float4*)(rowp + eB);
            if (r >= PAD && r < PAD + TH1)
                *(float4*)&outp[((ty0 + r - PAD) << 9) + gx0] = fC;
            *(float4*)&sHmax[r * SHP + x0] = hquad<true>(fA, fB, fC, fD, fE);
            *(float4*)&sHmin[r * SHP + x0] = hquad<false>(fA, fB, fC, fD, fE);
        }
        __syncthreads();
        if (half == 0) {
            float4 o[2];
            vpool2<true>(sHmax, vy, vx, o);
            unsigned short* vp = vmaxh + (((size_t)(b * NCH + c)) << 18);
            int gbase = ((ty0 + vy) << 9) + tx0 + vx;
            *(ushort4*)&vp[gbase] = make_ushort4(f2h(o[0].x), f2h(o[0].y), f2h(o[0].z), f2h(o[0].w));
            *(ushort4*)&vp[gbase + 512] = make_ushort4(f2h(o[1].x), f2h(o[1].y), f2h(o[1].z), f2h(o[1].w));
            acc[0] = op4<true>(acc[0], o[0]);
            acc[1] = op4<true>(acc[1], o[1]);
        } else {
            float4 o[2];
            vpool2<false>(sHmin, vy, vx, o);
            acc[0] = op4<false>(acc[0], o[0]);
            acc[1] = op4<false>(acc[1], o[1]);
        }
        __syncthreads();
    }
    // ---- per-pixel key maps + per-sub (4 rows x 64 cols) key maxima ----
    unsigned gb = ((unsigned)b << 18) + ((ty0 + vy) << 9) + tx0 + vx;
    if (half == 0) {
        *(uint4*)&bcK[gb] =
            make_uint4(~mkey(acc[0].x), ~mkey(acc[0].y), ~mkey(acc[0].z), ~mkey(acc[0].w));
        *(uint4*)&bcK[gb + 512] =
            make_uint4(~mkey(acc[1].x), ~mkey(acc[1].y), ~mkey(acc[1].z), ~mkey(acc[1].w));
        float mn = fminf(fminf(fminf(acc[0].x, acc[0].y), fminf(acc[0].z, acc[0].w)),
                         fminf(fminf(acc[1].x, acc[1].y), fminf(acc[1].z, acc[1].w)));
#pragma unroll
        for (int s = 1; s < 32; s <<= 1) mn = fminf(mn, __shfl_xor(mn, s));
        if ((v & 31) == 0)
            subkey[(BATCH + b) * NSUB + tile * 4 + (rg >> 1)] = ~mkey(mn);
    } else {
        *(uint4*)&dcK[gb] =
            make_uint4(mkey(acc[0].x), mkey(acc[0].y), mkey(acc[0].z), mkey(acc[0].w));
        *(uint4*)&dcK[gb + 512] =
            make_uint4(mkey(acc[1].x), mkey(acc[1].y), mkey(acc[1].z), mkey(acc[1].w));
        float mx = fmaxf(fmaxf(fmaxf(acc[0].x, acc[0].y), fmaxf(acc[0].z, acc[0].w)),
                         fmaxf(fmaxf(acc[1].x, acc[1].y), fmaxf(acc[1].z, acc[1].w)));
#pragma unroll
        for (int s = 1; s < 32; s <<= 1) mx = fmaxf(mx, __shfl_xor(mx, s));
        if ((v & 31) == 0)
            subkey[b * NSUB + tile * 4 + (rg >> 1)] = mkey(mx);
    }
}

// ---------------------------------------------------------------------------
// K2: fused tau + gather + last-block merge. 256 blocks (8/pair), NO grid
// sync. Phase A (all blocks): wave 0 redundantly computes its pair's tau =
// 26th-largest per-sub key-max (theorem: the 26 largest sub-maxima sit at 26
// distinct pixels, all >= tau, so {key >= tau} contains the lexicographic
// top-26) + ballot-compacts qualifying subs; all 4 waves gather the block's
// sub-slice with one aggregated atomicAdd per iteration. Then the canonical
// done-counter pattern (__threadfence release / acquire, device-scope per
// G16) elects the LAST block of each pair, which runs the r18-proven merge:
// LDS-tiled 26 block-max rounds with cached per-thread slice max.
// map0 (dc): A1 (argmax of per-pixel channel max, first occurrence).
// map1 (bc): partial A2 sums for EVERY batch (faithful to the reference's
// batch-mixing bug): 48 serial 26-element sums + one atomicAdd each.
__global__ __launch_bounds__(256) void taugather_merge_kernel(
    const unsigned* __restrict__ keys, const unsigned* __restrict__ subkey,
    const float* __restrict__ img, int* __restrict__ nCand,
    unsigned long long* __restrict__ cand, int* __restrict__ done,
    float* __restrict__ A1, float* __restrict__ A2sum) {
    int blk = blockIdx.x;
    int pair = blk >> 3;
    int bslot = blk & 7;
    int map = pair >> 4, b = pair & 15;
    int t = threadIdx.x;
    int wv = t >> 6, lane = t & 63;
    __shared__ __align__(16) unsigned long long sC[LDSCAP];  // merge tile
    int* sList = (int*)sC;                                   // alias: gather-phase sub list (4 KB)
    __shared__ unsigned long long sB[4];
    __shared__ unsigned long long sWin[K];
    __shared__ float sM[K];
    __shared__ int sIdx[K];
    __shared__ unsigned sTau;
    __shared__ int sN;
    __shared__ int sW[4];
    __shared__ int sBase;
    __shared__ int sIsLast;

    // ---- Phase A: tau + compaction (wave 0), then gather (all waves) ----
    if (wv == 0) {
        const unsigned* sk = subkey + (size_t)pair * NSUB + lane * 16;
        unsigned ko[16];
        *(uint4*)&ko[0] = *(const uint4*)&sk[0];
        *(uint4*)&ko[4] = *(const uint4*)&sk[4];
        *(uint4*)&ko[8] = *(const uint4*)&sk[8];
        *(uint4*)&ko[12] = *(const uint4*)&sk[12];
        unsigned long long q[16];
#pragma unroll
        for (int j = 0; j < 16; ++j)
            q[j] = ((unsigned long long)ko[j] << 32) | (unsigned)(lane * 16 + j);
        unsigned tv = 0;
        for (int r = 0; r < K; ++r) {
            unsigned long long m0 = q[0] > q[1] ? q[0] : q[1];
            unsigned long long m1 = q[2] > q[3] ? q[2] : q[3];
            unsigned long long m2 = q[4] > q[5] ? q[4] : q[5];
            unsigned long long m3 = q[6] > q[7] ? q[6] : q[7];
            unsigned long long m4 = q[8] > q[9] ? q[8] : q[9];
            unsigned long long m5 = q[10] > q[11] ? q[10] : q[11];
            unsigned long long m6 = q[12] > q[13] ? q[12] : q[13];
            unsigned long long m7 = q[14] > q[15] ? q[14] : q[15];
            m0 = m0 > m1 ? m0 : m1;
            m2 = m2 > m3 ? m2 : m3;
            m4 = m4 > m5 ? m4 : m5;
            m6 = m6 > m7 ? m6 : m7;
            m0 = m0 > m2 ? m0 : m2;
            m4 = m4 > m6 ? m4 : m6;
            unsigned long long m = m0 > m4 ? m0 : m4;
#pragma unroll
            for (int s = 1; s < 64; s <<= 1) {
                unsigned long long o = shfl_xor_u64(m, s);
                m = o > m ? o : m;
            }
            if (r == K - 1) tv = (unsigned)(m >> 32);
#pragma unroll
            for (int j = 0; j < 16; ++j)
                if (q[j] == m) q[j] = 0;
        }
        unsigned long long lt = (1ull << lane) - 1ull;
        int base = 0;
#pragma unroll
        for (int j = 0; j < 16; ++j) {
            bool qq = ko[j] >= tv;
            unsigned long long mk = __ballot(qq);
            if (qq) sList[base + (int)__popcll(mk & lt)] = lane * 16 + j;
            base += (int)__popcll(mk);
        }
        if (lane == 0) { sTau = tv; sN = base; }
    }
    __syncthreads();
    {
        unsigned tv = sTau;
        int n = sN;
        const unsigned* kp = keys + ((size_t)pair << 18);
        unsigned long long* cp = cand + (size_t)pair * CAP;
        int row = t >> 6, col = t & 63;
        for (int si = bslot; si < n; si += 8) {
            int sub = sList[si];
            int tile = sub >> 2, sr = sub & 3;
            int xs = (tile & 7) << 6;
            int ys = ((tile >> 3) << 4) + (sr << 2);
            int p = ((ys + row) << 9) + xs + col;
            unsigned k = kp[p];
            bool q = k >= tv;
            unsigned long long mk = __ballot(q);
            int cnt = (int)__popcll(mk);
            if (lane == 0) sW[wv] = cnt;
            __syncthreads();
            if (t == 0) {
                int a0 = sW[0], a1 = sW[1], a2 = sW[2], a3 = sW[3];
                int tot = a0 + a1 + a2 + a3;
                sBase = tot ? atomicAdd(&nCand[pair], tot) : 0;
                sW[0] = 0; sW[1] = a0; sW[2] = a0 + a1; sW[3] = a0 + a1 + a2;
            }
            __syncthreads();
            if (q) {
                int slot = sBase + sW[wv] + (int)__popcll(mk & ((1ull << lane) - 1ull));
                if (slot < CAP)
                    cp[slot] = ((unsigned long long)k << 32) | (unsigned)(0x7FFFFFFF - p);
            }
            __syncthreads();
        }
    }
    // ---- elect last block of this pair (release/acquire via threadfence) ----
    __threadfence();
    __syncthreads();
    if (t == 0) sIsLast = (atomicAdd(&done[pair], 1) == 7);
    __syncthreads();
    if (!sIsLast) return;
    __threadfence();

    // ---- Phase B: merge (last block only; r18-proven body) ----
    int n = nCand[pair];
    n = n < CAP ? n : CAP;
    const unsigned long long* cp = cand + (size_t)pair * CAP;
    int ntile = (n + LDSCAP - 1) / LDSCAP;
    unsigned long long kc = 0;
    for (int tl = 0; tl < ntile; ++tl) {
        int lo = tl * LDSCAP;
        int m = n - lo; m = m > LDSCAP ? LDSCAP : m;
        __syncthreads();                 // sList alias dead; safe to overwrite
        for (int i = t; i < m; i += 256) sC[i] = cp[lo + i];
        if (tl > 0) kc = (t < K) ? sWin[t] : 0ull;
        __syncthreads();
        unsigned long long lm = 0;
        int slot = -1;
        for (int i = t; i < m; i += 256) {
            unsigned long long v = sC[i];
            if (v > lm) { lm = v; slot = i; }
        }
        for (int r = 0; r < K; ++r) {
            unsigned long long mm = lm > kc ? lm : kc;
#pragma unroll
            for (int s = 1; s < 64; s <<= 1) {
                unsigned long long o = shfl_xor_u64(mm, s);
                mm = o > mm ? o : mm;
            }
            if (lane == 0) sB[wv] = mm;
            __syncthreads();
            unsigned long long wb = sB[0];
            if (sB[1] > wb) wb = sB[1];
            if (sB[2] > wb) wb = sB[2];
            if (sB[3] > wb) wb = sB[3];
            if (t == 0) sWin[r] = wb;
            if (wb == lm && slot >= 0) {    // owner: remove + rescan own slice
                sC[slot] = 0ull;
                lm = 0; slot = -1;
                for (int i = t; i < m; i += 256) {
                    unsigned long long v = sC[i];
                    if (v > lm) { lm = v; slot = i; }
                }
            }
            if (wb == kc) kc = 0ull;
            __syncthreads();
        }
    }
    if (t < K) sIdx[t] = 0x7FFFFFFF - (int)(unsigned)(sWin[t] & 0xFFFFFFFFull);
    __syncthreads();
    if (map == 0) {
        if (t < K) {
            int p = sIdx[t];
            float m = img[(((size_t)(b * NCH + 0)) << 18) + p];
            m = fmaxf(m, img[(((size_t)(b * NCH + 1)) << 18) + p]);
            m = fmaxf(m, img[(((size_t)(b * NCH + 2)) << 18) + p]);
            sM[t] = m;
        }
        __syncthreads();
        if (t == 0) {
            float bm = -FINF;
            int bj = 0;
            for (int j = 0; j < K; ++j)
                if (sM[j] > bm) { bm = sM[j]; bj = j; }   // strict > = first occurrence
            int p = sIdx[bj];
#pragma unroll
            for (int c = 0; c < NCH; ++c)
                A1[b * NCH + c] = img[(((size_t)(b * NCH + c)) << 18) + p];
        }
    } else {
        if (t < BATCH * NCH) {
            const float* xp = img + ((size_t)t << 18);
            float s = 0.0f;
            for (int j = 0; j < K; ++j) s += xp[sIdx[j]];
            atomicAdd(&A2sum[t], s);
        }
    }
}

__device__ __forceinline__ float tval(unsigned short a, unsigned short bq, unsigned short c,
                                      float r0, float r1, float r2) {
    return 1.0f - 0.95f * fminf(fminf(fmaf(-h2f(a), r0, r0), fmaf(-h2f(bq), r1, r1)),
                                fmaf(-h2f(c), r2, r2));
}

// ---------------------------------------------------------------------------
// K3: t = 1 - 0.95 * min_c (1 - M_c)*r_c, streaming fp16 Vmax at 16 B/lane
// (8 px/thread). r_c computed inline from A1/A2sum (broadcast loads).
// x-channels of out were already written by pool_maps.
__global__ __launch_bounds__(256) void final_t_kernel(
    const unsigned short* __restrict__ vmaxh, const float* __restrict__ A1,
    const float* __restrict__ A2sum, float* __restrict__ out) {
    int i8 = (blockIdx.x * 256 + threadIdx.x) << 3;
    int b = i8 >> 18;
    int p = i8 & (HW - 1);
    const unsigned short* vp = vmaxh + (((size_t)(b * NCH)) << 18) + p;
    const float invBK = 1.0f / (float)BK;
    float A0 = 0.75f * A1[b * NCH + 0] + 0.25f * (A2sum[b * NCH + 0] * invBK);
    float Ab = 0.75f * A1[b * NCH + 1] + 0.25f * (A2sum[b * NCH + 1] * invBK);
    float Ac = 0.75f * A1[b * NCH + 2] + 0.25f * (A2sum[b * NCH + 2] * invBK);
    float r0 = 1.0f / ((1.0f - A0) + 1e-6f);
    float r1 = 1.0f / ((1.0f - Ab) + 1e-6f);
    float r2 = 1.0f / ((1.0f - Ac) + 1e-6f);
    ushort4 v0a = *(const ushort4*)(vp);
    ushort4 v0b = *(const ushort4*)(vp + 4);
    ushort4 v1a = *(const ushort4*)(vp + (1 << 18));
    ushort4 v1b = *(const ushort4*)(vp + (1 << 18) + 4);
    ushort4 v2a = *(const ushort4*)(vp + (2 << 18));
    ushort4 v2b = *(const ushort4*)(vp + (2 << 18) + 4);
    float4 ta, tb;
    ta.x = tval(v0a.x, v1a.x, v2a.x, r0, r1, r2);
    ta.y = tval(v0a.y, v1a.y, v2a.y, r0, r1, r2);
    ta.z = tval(v0a.z, v1a.z, v2a.z, r0, r1, r2);
    ta.w = tval(v0a.w, v1a.w, v2a.w, r0, r1, r2);
    tb.x = tval(v0b.x, v1b.x, v2b.x, r0, r1, r2);
    tb.y = tval(v0b.y, v1b.y, v2b.y, r0, r1, r2);
    tb.z = tval(v0b.z, v1b.z, v2b.z, r0, r1, r2);
    tb.w = tval(v0b.w, v1b.w, v2b.w, r0, r1, r2);
    float* op3 = out + (((size_t)(b * 4 + 3)) << 18) + p;
    *(float4*)op3 = ta;
    *(float4*)(op3 + 4) = tb;
}

// ---------------------------------------------------------------------------
extern "C" void kernel_launch(void* const* d_in, const int* in_sizes, int n_in,
                              void* d_out, int out_size, void* d_ws, size_t ws_size,
                              hipStream_t stream) {
    const float* x = (const float*)d_in[0];
    float* out = (float*)d_out;

    const size_t nPix = (size_t)BATCH * HW;      // 4,194,304
    const size_t nCh = (size_t)BATCH * NCH * HW; // 12,582,912

    unsigned long long* cand = (unsigned long long*)d_ws;        // 8 MB
    unsigned* dcK = (unsigned*)(cand + (size_t)NPAIR * CAP);     // 16 MB
    unsigned* bcK = dcK + nPix;                                  // 16 MB (contiguous with dcK)
    unsigned short* vmaxh = (unsigned short*)(bcK + nPix);       // 24 MB fp16
    unsigned* subkey = (unsigned*)(vmaxh + nCh);                 // [2][16][1024]
    int* nCand = (int*)(subkey + (size_t)NPAIR * NSUB);
    int* done = nCand + NPAIR;
    float* A1 = (float*)(done + NPAIR);
    float* A2sum = A1 + BATCH * NCH;

    pool_maps_kernel<<<BATCH * 256, 256, 0, stream>>>(x, vmaxh, dcK, bcK, subkey, out,
                                                      nCand, A2sum, done);
    taugather_merge_kernel<<<NPAIR * 8, 256, 0, stream>>>(dcK, subkey, x, nCand, cand,
                                                          done, A1, A2sum);
    final_t_kernel<<<(int)(nPix / 8 / 256), 256, 0, stream>>>(vmaxh, A1, A2sum, out);
}

// Round 20
// 77.704 us; speedup vs baseline: 1.3376x; 1.3376x over previous
//
#include <hip/hip_runtime.h>
#include <hip/hip_bf16.h>
#include <hip/hip_fp16.h>

// Problem constants (fixed by setup_inputs)
#define BATCH 16
#define NCH 3
#define H 512
#define W 512
#define HW (H * W)          // 262144 = 2^18
#define PAD 7
#define K 26                // int(0.0001 * 512 * 512)
#define NSUB 1024           // subs (4 rows x 64 cols = 256 px) per batch
#define NPAIR 32            // 2 maps x 16 batches
#define BK (BATCH * K)      // 416
#define CAP 32768           // candidate list capacity per pair
#define LDSCAP 6144         // merge LDS tile (48 KB)

#define TH1 16              // pool tile height
#define ROWS1 30            // TH1 + 14
#define SHP 68              // padded LDS stride for h-pool rows (64 used)

#define FINF __builtin_inff()

// monotone float->u32 key (order-preserving for all floats)
__device__ __forceinline__ unsigned mkey(float f) {
    unsigned u = __float_as_uint(f);
    unsigned m = (unsigned)(((int)u) >> 31) | 0x80000000u;
    return u ^ m;
}

__device__ __forceinline__ unsigned short f2h(float f) {
    __half h = __float2half(f);
    return *reinterpret_cast<unsigned short*>(&h);
}
__device__ __forceinline__ float h2f(unsigned short s) {
    __half h = *reinterpret_cast<__half*>(&s);
    return __half2float(h);
}

__device__ __forceinline__ unsigned long long shfl_xor_u64(unsigned long long v, int m) {
    int lo = __shfl_xor((int)(unsigned)(v & 0xFFFFFFFFull), m);
    int hi = __shfl_xor((int)(unsigned)(v >> 32), m);
    return ((unsigned long long)(unsigned)hi << 32) | (unsigned)lo;
}

template <bool MX>
__device__ __forceinline__ float op(float a, float b) { return MX ? fmaxf(a, b) : fminf(a, b); }
template <bool MX>
__device__ __forceinline__ float4 op4(float4 a, float4 b) {
    return make_float4(op<MX>(a.x, b.x), op<MX>(a.y, b.y), op<MX>(a.z, b.z), op<MX>(a.w, b.w));
}

// horizontal 15-window pool of a 4-output group from 5 clamped-base float4s
template <bool MX>
__device__ __forceinline__ float4 hquad(float4 fA, float4 fB, float4 fC, float4 fD, float4 fE) {
    float4 m4 = op4<MX>(op4<MX>(fB, fC), fD);
    float tm = op<MX>(op<MX>(m4.x, m4.y), op<MX>(m4.z, m4.w));
    return make_float4(
        op<MX>(tm, op<MX>(fA.y, op<MX>(fA.z, fA.w))),
        op<MX>(tm, op<MX>(fA.z, op<MX>(fA.w, fE.x))),
        op<MX>(tm, op<MX>(fA.w, op<MX>(fE.x, fE.y))),
        op<MX>(tm, op<MX>(fE.x, op<MX>(fE.y, fE.z))));
}

// v-pool of 2 consecutive output rows from 16 LDS rows (14-row shared core)
template <bool MX>
__device__ __forceinline__ void vpool2(const float* __restrict__ sH, int vy, int vx,
                                       float4 o[2]) {
    const float* p0 = sH + vy * SHP + vx;
    float4 t4 = *(const float4*)(p0 + SHP);
#pragma unroll
    for (int j = 2; j <= 14; ++j) t4 = op4<MX>(t4, *(const float4*)(p0 + j * SHP));
    float4 r0 = *(const float4*)(p0);
    float4 r15 = *(const float4*)(p0 + 15 * SHP);
    o[0] = op4<MX>(r0, t4);
    o[1] = op4<MX>(t4, r15);
}

// ---------------------------------------------------------------------------
// K1 (r12/r14/r16/r18-proven): 64x16 tiles, LDS 16.3 KB -> 8 blocks/CU, grid
// 4096 = exactly 2 full rounds. Per channel: h-pool straight from global (5
// clamped-base float4 loads per 4-output group == exact clamp-to-edge), max
// AND min from the same loads into two LDS buffers; x->out copy rides on the
// center float4. v-pool half-split: u<128 -> max map (fp16 Vmax + bc keys),
// u>=128 -> min map (dc keys). Emits per-sub (4x64) key maxima. Blocks 0..47
// also zero nCand / A2sum (stream order guarantees visibility downstream).
__global__ __launch_bounds__(256, 8) void pool_maps_kernel(
    const float* __restrict__ x, unsigned short* __restrict__ vmaxh,
    unsigned* __restrict__ dcK, unsigned* __restrict__ bcK,
    unsigned* __restrict__ subkey, float* __restrict__ out,
    int* __restrict__ nCand, float* __restrict__ A2sum) {
    __shared__ __align__(16) float sHmax[ROWS1 * SHP];
    __shared__ __align__(16) float sHmin[ROWS1 * SHP];
    int blk = blockIdx.x;
    if (threadIdx.x == 0) {
        if (blk < NPAIR) nCand[blk] = 0;
        if (blk < BATCH * NCH) A2sum[blk] = 0.0f;
    }
    int b = blk >> 8;
    int tile = blk & 255;          // 8 cols x 32 rows of tiles
    int tx0 = (tile & 7) << 6;
    int ty0 = (tile >> 3) << 4;
    int u = threadIdx.x;
    int half = u >> 7;      // 0: max map (bc + Vmax), 1: min map (dc)
    int v = u & 127;
    int rg = v >> 4;        // 0..7 row-pairs
    int cg = v & 15;
    int vx = cg << 2;
    int vy = rg << 1;       // 0,2,..,14
    float4 acc[2];
    float ainit = half ? FINF : -FINF;
    acc[0] = acc[1] = make_float4(ainit, ainit, ainit, ainit);

    for (int c = 0; c < NCH; ++c) {
        const float* xp = x + (((size_t)(b * NCH + c)) << 18);
        float* outp = out + (((size_t)(b * 4 + c)) << 18);
        for (int it = u; it < ROWS1 * 16; it += 256) {
            int r = it >> 4;
            int x0 = (it & 15) << 2;
            int gy = ty0 - PAD + r;
            gy = gy < 0 ? 0 : (gy > H - 1 ? H - 1 : gy);
            const float* rowp = xp + (gy << 9);
            int gx0 = tx0 + x0;
            int aB = gx0 - 8; aB = aB < 0 ? 0 : aB;
            int bB = gx0 - 4; bB = bB < 0 ? 0 : bB;
            int dB = gx0 + 4; dB = dB > W - 4 ? W - 4 : dB;
            int eB = gx0 + 8; eB = eB > W - 4 ? W - 4 : eB;
            float4 fA = *(const float4*)(rowp + aB);
            float4 fB = *(const float4*)(rowp + bB);
            float4 fC = *(const float4*)(rowp + gx0);
            float4 fD = *(const float4*)(rowp + dB);
            float4 fE = *(const float4*)(rowp + eB);
            if (r >= PAD && r < PAD + TH1)
                *(float4*)&outp[((ty0 + r - PAD) << 9) + gx0] = fC;
            *(float4*)&sHmax[r * SHP + x0] = hquad<true>(fA, fB, fC, fD, fE);
            *(float4*)&sHmin[r * SHP + x0] = hquad<false>(fA, fB, fC, fD, fE);
        }
        __syncthreads();
        if (half == 0) {
            float4 o[2];
            vpool2<true>(sHmax, vy, vx, o);
            unsigned short* vp = vmaxh + (((size_t)(b * NCH + c)) << 18);
            int gbase = ((ty0 + vy) << 9) + tx0 + vx;
            *(ushort4*)&vp[gbase] = make_ushort4(f2h(o[0].x), f2h(o[0].y), f2h(o[0].z), f2h(o[0].w));
            *(ushort4*)&vp[gbase + 512] = make_ushort4(f2h(o[1].x), f2h(o[1].y), f2h(o[1].z), f2h(o[1].w));
            acc[0] = op4<true>(acc[0], o[0]);
            acc[1] = op4<true>(acc[1], o[1]);
        } else {
            float4 o[2];
            vpool2<false>(sHmin, vy, vx, o);
            acc[0] = op4<false>(acc[0], o[0]);
            acc[1] = op4<false>(acc[1], o[1]);
        }
        __syncthreads();
    }
    // ---- per-pixel key maps + per-sub (4 rows x 64 cols) key maxima ----
    unsigned gb = ((unsigned)b << 18) + ((ty0 + vy) << 9) + tx0 + vx;
    if (half == 0) {
        *(uint4*)&bcK[gb] =
            make_uint4(~mkey(acc[0].x), ~mkey(acc[0].y), ~mkey(acc[0].z), ~mkey(acc[0].w));
        *(uint4*)&bcK[gb + 512] =
            make_uint4(~mkey(acc[1].x), ~mkey(acc[1].y), ~mkey(acc[1].z), ~mkey(acc[1].w));
        float mn = fminf(fminf(fminf(acc[0].x, acc[0].y), fminf(acc[0].z, acc[0].w)),
                         fminf(fminf(acc[1].x, acc[1].y), fminf(acc[1].z, acc[1].w)));
#pragma unroll
        for (int s = 1; s < 32; s <<= 1) mn = fminf(mn, __shfl_xor(mn, s));
        if ((v & 31) == 0)
            subkey[(BATCH + b) * NSUB + tile * 4 + (rg >> 1)] = ~mkey(mn);
    } else {
        *(uint4*)&dcK[gb] =
            make_uint4(mkey(acc[0].x), mkey(acc[0].y), mkey(acc[0].z), mkey(acc[0].w));
        *(uint4*)&dcK[gb + 512] =
            make_uint4(mkey(acc[1].x), mkey(acc[1].y), mkey(acc[1].z), mkey(acc[1].w));
        float mx = fmaxf(fmaxf(fmaxf(acc[0].x, acc[0].y), fmaxf(acc[0].z, acc[0].w)),
                         fmaxf(fmaxf(acc[1].x, acc[1].y), fmaxf(acc[1].z, acc[1].w)));
#pragma unroll
        for (int s = 1; s < 32; s <<= 1) mx = fmaxf(mx, __shfl_xor(mx, s));
        if ((v & 31) == 0)
            subkey[b * NSUB + tile * 4 + (rg >> 1)] = mkey(mx);
    }
}

// ---------------------------------------------------------------------------
// K2: fused tau + gather, 256 blocks (8/pair), NO cross-block sync, NO
// dependent shuffle chains, NO per-iteration barriers.
// Wave 0: tau by 32-step BINARY SEARCH on the key value — count(subkeys >=
// thr) via 16 independent ballot+popcount per step (scalar pipe; replaces the
// 26-round ds_bpermute butterfly that serialized r18's tail). Result: max v
// with count >= 26 == the 26th-largest subkey — identical tau, same theorem
// ({key >= tau} contains the lexicographic top-26). Then ballot-compact the
// qualifying subs. One __syncthreads; then each WAVE gathers whole subs
// independently (4 px/lane over the 4x64 sub) with one atomicAdd per sub.
__global__ __launch_bounds__(256) void taugather_kernel(
    const unsigned* __restrict__ keys, const unsigned* __restrict__ subkey,
    int* __restrict__ nCand, unsigned long long* __restrict__ cand) {
    int blk = blockIdx.x;
    int pair = blk >> 3;
    int bslot = blk & 7;
    int t = threadIdx.x;
    int wv = t >> 6, lane = t & 63;
    __shared__ int sList[NSUB];
    __shared__ unsigned sTau;
    __shared__ int sN;
    if (wv == 0) {
        const unsigned* sk = subkey + (size_t)pair * NSUB + lane * 16;
        unsigned ko[16];
        *(uint4*)&ko[0] = *(const uint4*)&sk[0];
        *(uint4*)&ko[4] = *(const uint4*)&sk[4];
        *(uint4*)&ko[8] = *(const uint4*)&sk[8];
        *(uint4*)&ko[12] = *(const uint4*)&sk[12];
        // binary search: largest tv with count(ko >= tv) >= K
        unsigned tv = 0;
#pragma unroll
        for (int bit = 31; bit >= 0; --bit) {
            unsigned cnd = tv | (1u << bit);
            int cnt = 0;
#pragma unroll
            for (int j = 0; j < 16; ++j)
                cnt += (int)__popcll(__ballot(ko[j] >= cnd));
            if (cnt >= K) tv = cnd;
        }
        // compact qualifying subs (subkey >= tv)
        unsigned long long lt = (1ull << lane) - 1ull;
        int base = 0;
#pragma unroll
        for (int j = 0; j < 16; ++j) {
            bool qq = ko[j] >= tv;
            unsigned long long mk = __ballot(qq);
            if (qq) sList[base + (int)__popcll(mk & lt)] = lane * 16 + j;
            base += (int)__popcll(mk);
        }
        if (lane == 0) { sTau = tv; sN = base; }
    }
    __syncthreads();
    unsigned tv = sTau;
    int n = sN;
    const unsigned* kp = keys + ((size_t)pair << 18);
    unsigned long long* cp = cand + (size_t)pair * CAP;
    unsigned long long lt = (1ull << lane) - 1ull;
    // wave-per-sub gather: no barriers, one atomic per sub
    for (int si = bslot * 4 + wv; si < n; si += 32) {
        int sub = sList[si];
        int tile = sub >> 2, sr = sub & 3;
        int xs = (tile & 7) << 6;
        int ys = ((tile >> 3) << 4) + (sr << 2);
        int p0 = (ys << 9) + xs + lane;
        unsigned k0 = kp[p0];
        unsigned k1 = kp[p0 + 512];
        unsigned k2 = kp[p0 + 1024];
        unsigned k3 = kp[p0 + 1536];
        bool q0 = k0 >= tv, q1 = k1 >= tv, q2 = k2 >= tv, q3 = k3 >= tv;
        unsigned long long m0 = __ballot(q0);
        unsigned long long m1 = __ballot(q1);
        unsigned long long m2 = __ballot(q2);
        unsigned long long m3 = __ballot(q3);
        int c0 = (int)__popcll(m0), c1 = (int)__popcll(m1);
        int c2 = (int)__popcll(m2), c3 = (int)__popcll(m3);
        int tot = c0 + c1 + c2 + c3;
        if (tot == 0) continue;
        int base = 0;
        if (lane == 0) base = atomicAdd(&nCand[pair], tot);
        base = __shfl(base, 0);
        if (q0) {
            int slot = base + (int)__popcll(m0 & lt);
            if (slot < CAP) cp[slot] = ((unsigned long long)k0 << 32) | (unsigned)(0x7FFFFFFF - p0);
        }
        if (q1) {
            int slot = base + c0 + (int)__popcll(m1 & lt);
            if (slot < CAP) cp[slot] = ((unsigned long long)k1 << 32) | (unsigned)(0x7FFFFFFF - (p0 + 512));
        }
        if (q2) {
            int slot = base + c0 + c1 + (int)__popcll(m2 & lt);
            if (slot < CAP) cp[slot] = ((unsigned long long)k2 << 32) | (unsigned)(0x7FFFFFFF - (p0 + 1024));
        }
        if (q3) {
            int slot = base + c0 + c1 + c2 + (int)__popcll(m3 & lt);
            if (slot < CAP) cp[slot] = ((unsigned long long)k3 << 32) | (unsigned)(0x7FFFFFFF - (p0 + 1536));
        }
    }
}

// ---------------------------------------------------------------------------
// K3: per-pair merge of nCand candidates -> global top-26 (r18-proven body).
// map0 (dc): A1 (argmax of per-pixel channel max, first occurrence).
// map1 (bc): partial A2 sums — this block's 26 indices contribute to EVERY
// batch's A2 (faithful to the reference's batch-mixing bug): 48 (batch,ch)
// serial 26-element sums + ONE atomicAdd each (768 atomics total).
__global__ __launch_bounds__(256) void merge_kernel(
    const unsigned long long* __restrict__ cand, const int* __restrict__ nCand,
    const float* __restrict__ img, float* __restrict__ A1, float* __restrict__ A2sum) {
    int pair = blockIdx.x;
    int map = pair >> 4, b = pair & 15;
    int t = threadIdx.x;
    int wv = t >> 6, lane = t & 63;
    int n = nCand[pair];
    n = n < CAP ? n : CAP;
    const unsigned long long* cp = cand + (size_t)pair * CAP;
    __shared__ unsigned long long sC[LDSCAP];
    __shared__ unsigned long long sB[4];
    __shared__ unsigned long long sWin[K];
    __shared__ float sM[K];
    __shared__ int sIdx[K];
    int ntile = (n + LDSCAP - 1) / LDSCAP;
    unsigned long long kc = 0;
    for (int tl = 0; tl < ntile; ++tl) {
        int lo = tl * LDSCAP;
        int m = n - lo; m = m > LDSCAP ? LDSCAP : m;
        for (int i = t; i < m; i += 256) sC[i] = cp[lo + i];
        if (tl > 0) kc = (t < K) ? sWin[t] : 0ull;
        __syncthreads();
        unsigned long long lm = 0;
        int slot = -1;
        for (int i = t; i < m; i += 256) {
            unsigned long long v = sC[i];
            if (v > lm) { lm = v; slot = i; }
        }
        for (int r = 0; r < K; ++r) {
            unsigned long long mm = lm > kc ? lm : kc;
#pragma unroll
            for (int s = 1; s < 64; s <<= 1) {
                unsigned long long o = shfl_xor_u64(mm, s);
                mm = o > mm ? o : mm;
            }
            if (lane == 0) sB[wv] = mm;
            __syncthreads();
            unsigned long long wb = sB[0];
            if (sB[1] > wb) wb = sB[1];
            if (sB[2] > wb) wb = sB[2];
            if (sB[3] > wb) wb = sB[3];
            if (t == 0) sWin[r] = wb;
            if (wb == lm && slot >= 0) {    // owner: remove + rescan own slice
                sC[slot] = 0ull;
                lm = 0; slot = -1;
                for (int i = t; i < m; i += 256) {
                    unsigned long long v = sC[i];
                    if (v > lm) { lm = v; slot = i; }
                }
            }
            if (wb == kc) kc = 0ull;
            __syncthreads();
        }
    }
    if (t < K) sIdx[t] = 0x7FFFFFFF - (int)(unsigned)(sWin[t] & 0xFFFFFFFFull);
    __syncthreads();
    if (map == 0) {
        if (t < K) {
            int p = sIdx[t];
            float m = img[(((size_t)(b * NCH + 0)) << 18) + p];
            m = fmaxf(m, img[(((size_t)(b * NCH + 1)) << 18) + p]);
            m = fmaxf(m, img[(((size_t)(b * NCH + 2)) << 18) + p]);
            sM[t] = m;
        }
        __syncthreads();
        if (t == 0) {
            float bm = -FINF;
            int bj = 0;
            for (int j = 0; j < K; ++j)
                if (sM[j] > bm) { bm = sM[j]; bj = j; }   // strict > = first occurrence
            int p = sIdx[bj];
#pragma unroll
            for (int c = 0; c < NCH; ++c)
                A1[b * NCH + c] = img[(((size_t)(b * NCH + c)) << 18) + p];
        }
    } else {
        if (t < BATCH * NCH) {
            const float* xp = img + ((size_t)t << 18);
            float s = 0.0f;
            for (int j = 0; j < K; ++j) s += xp[sIdx[j]];
            atomicAdd(&A2sum[t], s);
        }
    }
}

__device__ __forceinline__ float tval(unsigned short a, unsigned short bq, unsigned short c,
                                      float r0, float r1, float r2) {
    return 1.0f - 0.95f * fminf(fminf(fmaf(-h2f(a), r0, r0), fmaf(-h2f(bq), r1, r1)),
                                fmaf(-h2f(c), r2, r2));
}

// ---------------------------------------------------------------------------
// K4: t = 1 - 0.95 * min_c (1 - M_c)*r_c, streaming fp16 Vmax at 16 B/lane
// (8 px/thread). r_c computed inline from A1/A2sum (broadcast loads).
// x-channels of out were already written by pool_maps.
__global__ __launch_bounds__(256) void final_t_kernel(
    const unsigned short* __restrict__ vmaxh, const float* __restrict__ A1,
    const float* __restrict__ A2sum, float* __restrict__ out) {
    int i8 = (blockIdx.x * 256 + threadIdx.x) << 3;
    int b = i8 >> 18;
    int p = i8 & (HW - 1);
    const unsigned short* vp = vmaxh + (((size_t)(b * NCH)) << 18) + p;
    const float invBK = 1.0f / (float)BK;
    float A0 = 0.75f * A1[b * NCH + 0] + 0.25f * (A2sum[b * NCH + 0] * invBK);
    float Ab = 0.75f * A1[b * NCH + 1] + 0.25f * (A2sum[b * NCH + 1] * invBK);
    float Ac = 0.75f * A1[b * NCH + 2] + 0.25f * (A2sum[b * NCH + 2] * invBK);
    float r0 = 1.0f / ((1.0f - A0) + 1e-6f);
    float r1 = 1.0f / ((1.0f - Ab) + 1e-6f);
    float r2 = 1.0f / ((1.0f - Ac) + 1e-6f);
    ushort4 v0a = *(const ushort4*)(vp);
    ushort4 v0b = *(const ushort4*)(vp + 4);
    ushort4 v1a = *(const ushort4*)(vp + (1 << 18));
    ushort4 v1b = *(const ushort4*)(vp + (1 << 18) + 4);
    ushort4 v2a = *(const ushort4*)(vp + (2 << 18));
    ushort4 v2b = *(const ushort4*)(vp + (2 << 18) + 4);
    float4 ta, tb;
    ta.x = tval(v0a.x, v1a.x, v2a.x, r0, r1, r2);
    ta.y = tval(v0a.y, v1a.y, v2a.y, r0, r1, r2);
    ta.z = tval(v0a.z, v1a.z, v2a.z, r0, r1, r2);
    ta.w = tval(v0a.w, v1a.w, v2a.w, r0, r1, r2);
    tb.x = tval(v0b.x, v1b.x, v2b.x, r0, r1, r2);
    tb.y = tval(v0b.y, v1b.y, v2b.y, r0, r1, r2);
    tb.z = tval(v0b.z, v1b.z, v2b.z, r0, r1, r2);
    tb.w = tval(v0b.w, v1b.w, v2b.w, r0, r1, r2);
    float* op3 = out + (((size_t)(b * 4 + 3)) << 18) + p;
    *(float4*)op3 = ta;
    *(float4*)(op3 + 4) = tb;
}

// ---------------------------------------------------------------------------
extern "C" void kernel_launch(void* const* d_in, const int* in_sizes, int n_in,
                              void* d_out, int out_size, void* d_ws, size_t ws_size,
                              hipStream_t stream) {
    const float* x = (const float*)d_in[0];
    float* out = (float*)d_out;

    const size_t nPix = (size_t)BATCH * HW;      // 4,194,304
    const size_t nCh = (size_t)BATCH * NCH * HW; // 12,582,912

    unsigned long long* cand = (unsigned long long*)d_ws;        // 8 MB
    unsigned* dcK = (unsigned*)(cand + (size_t)NPAIR * CAP);     // 16 MB
    unsigned* bcK = dcK + nPix;                                  // 16 MB (contiguous with dcK)
    unsigned short* vmaxh = (unsigned short*)(bcK + nPix);       // 24 MB fp16
    unsigned* subkey = (unsigned*)(vmaxh + nCh);                 // [2][16][1024]
    int* nCand = (int*)(subkey + (size_t)NPAIR * NSUB);
    float* A1 = (float*)(nCand + NPAIR);
    float* A2sum = A1 + BATCH * NCH;

    pool_maps_kernel<<<BATCH * 256, 256, 0, stream>>>(x, vmaxh, dcK, bcK, subkey, out,
                                                      nCand, A2sum);
    taugather_kernel<<<NPAIR * 8, 256, 0, stream>>>(dcK, subkey, nCand, cand);
    merge_kernel<<<NPAIR, 256, 0, stream>>>(cand, nCand, x, A1, A2sum);
    final_t_kernel<<<(int)(nPix / 8 / 256), 256, 0, stream>>>(vmaxh, A1, A2sum, out);
}